// Round 3
// baseline (467.862 us; speedup 1.0000x reference)
//
#include <hip/hip_runtime.h>
#include <hip/hip_bf16.h>
#include <cstdint>
#include <cstddef>

#define SEQ    4096
#define DM     2048
#define DH     128
#define NH     16
#define NKV    4
#define NC     3072          // qkv output columns: 2048 q | 512 k | 512 v
#define KOFF   2048
#define VOFF   2560
// 1/sqrt(128) * log2(e): q pre-scale so softmax runs in base-2 (exp2)
#define Q_SCALE 0.12751730f

using bf16 = __hip_bfloat16;
typedef __bf16 bf16x8 __attribute__((ext_vector_type(8)));
typedef float f32x4 __attribute__((ext_vector_type(4)));
typedef float f32x16 __attribute__((ext_vector_type(16)));

static __device__ inline float bf2f(bf16 x) { return __bfloat162float(x); }
static __device__ inline bf16 f2bf(float x) { return __float2bfloat16(x); }

// async global->LDS, 16B per lane. LDS dest = wave-uniform base + lane*16.
static __device__ inline void load_lds16(const bf16* g, bf16* l) {
    __builtin_amdgcn_global_load_lds(
        (const __attribute__((address_space(1))) uint32_t*)g,
        (__attribute__((address_space(3))) uint32_t*)l, 16, 0, 0);
}

// ---------------- x: f32 -> bf16 ----------------
__global__ void xconv(const float* __restrict__ in, bf16* __restrict__ out) {
    int i = blockIdx.x * 256 + threadIdx.x;   // one float4 per thread
    float4 v = ((const float4*)in)[i];
    bf16 a = f2bf(v.x), b = f2bf(v.y), c = f2bf(v.z), d = f2bf(v.w);
    ushort4 u;
    u.x = *(unsigned short*)&a; u.y = *(unsigned short*)&b;
    u.z = *(unsigned short*)&c; u.w = *(unsigned short*)&d;
    ((ushort4*)out)[i] = u;
}

// ---------------- prep: weight transposes (f32 -> bf16) + bias concat ----------------
__global__ void prep_wqkv(const float* __restrict__ WQ, const float* __restrict__ WK,
                          const float* __restrict__ WV, bf16* __restrict__ wt) {
    int m = blockIdx.x * 256 + threadIdx.x;   // 0..2047
    int j = blockIdx.y;                       // 0..3071
    float v;
    if (j < KOFF)      { v = WQ[((size_t)(j >> 7) * DM + m) * DH + (j & 127)]; }
    else if (j < VOFF) { int jj = j - KOFF; v = WK[((size_t)(jj >> 7) * DM + m) * DH + (jj & 127)]; }
    else               { int jj = j - VOFF; v = WV[((size_t)(jj >> 7) * DM + m) * DH + (jj & 127)]; }
    wt[(size_t)j * DM + m] = f2bf(v);
}

__global__ void prep_wo(const float* __restrict__ WO, bf16* __restrict__ wt) {
    int m = blockIdx.x * 256 + threadIdx.x;
    int j = blockIdx.y;
    wt[(size_t)j * DM + m] = f2bf(WO[(size_t)m * DM + j]);
}

__global__ void prep_bias(const float* __restrict__ bQ, const float* __restrict__ bK,
                          const float* __restrict__ bV, float* __restrict__ bias) {
    int j = blockIdx.x * 256 + threadIdx.x;
    if (j >= NC) return;
    bias[j] = (j < KOFF) ? bQ[j] : (j < VOFF ? bK[j - KOFF] : bV[j - VOFF]);
}

// ---------------- GEMM: C[M][N] = A[M][2048] * Bt[N][2048]^T + bias ----------------
#define BM 128
#define BN 128
#define BK 64

template <typename OutT>
__global__ __launch_bounds__(256)
void gemm_bt(const bf16* __restrict__ A, const bf16* __restrict__ Bt,
             const float* __restrict__ bias, OutT* __restrict__ C, int N) {
    __shared__ __align__(16) bf16 As[BM * BK];   // 16 KB, linear [128][64]
    __shared__ __align__(16) bf16 Bs[BN * BK];   // 16 KB
    const int tid = threadIdx.x;
    const int wave = tid >> 6, lane = tid & 63;
    const int quad = lane >> 4, l15 = lane & 15;
    const int wm = (wave >> 1) * 64, wn = (wave & 1) * 64;
    const int m0 = blockIdx.y * BM, n0 = blockIdx.x * BN;

    f32x4 acc[4][4] = {};

    const bf16* gsrc = (wave < 2)
        ? A  + (size_t)(m0 + (wave & 1) * 64) * DM
        : Bt + (size_t)(n0 + (wave & 1) * 64) * DM;
    bf16* lbase = (wave < 2 ? As : Bs) + (wave & 1) * 64 * BK;
    const int lrow = lane >> 3;                          // 0..7
    const int gslot = (lane & 7) ^ lrow;                 // swizzled source slot
    const bf16* gp = gsrc + (size_t)lrow * DM + gslot * 8;

    const int rsw = l15 & 7;

    for (int k0 = 0; k0 < DM; k0 += BK) {
        __syncthreads();
        #pragma unroll
        for (int cc = 0; cc < 8; ++cc)
            load_lds16(gp + (size_t)cc * 8 * DM + k0, lbase + cc * 8 * BK);
        __syncthreads();

        #pragma unroll
        for (int ks = 0; ks < 2; ++ks) {
            bf16x8 af[4], bfr[4];
            #pragma unroll
            for (int i = 0; i < 4; ++i)
                af[i] = *(const bf16x8*)&As[(wm + i * 16 + l15) * BK + (((ks * 4 + quad) ^ rsw) * 8)];
            #pragma unroll
            for (int j = 0; j < 4; ++j)
                bfr[j] = *(const bf16x8*)&Bs[(wn + j * 16 + l15) * BK + (((ks * 4 + quad) ^ rsw) * 8)];
            #pragma unroll
            for (int i = 0; i < 4; ++i)
                #pragma unroll
                for (int j = 0; j < 4; ++j)
                    acc[i][j] = __builtin_amdgcn_mfma_f32_16x16x32_bf16(af[i], bfr[j], acc[i][j], 0, 0, 0);
        }
    }

    #pragma unroll
    for (int i = 0; i < 4; ++i) {
        int row = m0 + wm + i * 16 + quad * 4;
        #pragma unroll
        for (int j = 0; j < 4; ++j) {
            int col = n0 + wn + j * 16 + l15;
            float bv = bias[col];
            #pragma unroll
            for (int r = 0; r < 4; ++r) {
                float val = acc[i][j][r] + bv;
                if constexpr (sizeof(OutT) == 2)
                    C[(size_t)(row + r) * N + col] = f2bf(val);
                else
                    C[(size_t)(row + r) * N + col] = val;
            }
        }
    }
}

// ---------------- rotary: precomputed cos/sin table ----------------
// tab[s*64 + i] = (cos(s*w_i), sin(s*w_i)); computed once into dead xb region.
__global__ void sctab(float2* __restrict__ tab) {
    int idx = blockIdx.x * 256 + threadIdx.x;   // 0..262143
    int s = idx >> 6, i = idx & 63;
    float inv_freq = __expf(-(float)i * 0.14391156831212788f);
    float ang = (float)s * inv_freq;
    float2 cs;
    cs.x = cosf(ang);
    cs.y = sinf(ang);
    tab[idx] = cs;
}

__global__ void rotary(bf16* __restrict__ qkv, const float2* __restrict__ tab) {
    int idx = blockIdx.x * 256 + threadIdx.x;
    const int QP = SEQ * (NH * DH / 2);
    int s, col, i; float scale;
    if (idx < QP) {
        s = idx >> 10; int p = idx & 1023;
        col = ((p >> 6) * DH) + 2 * (p & 63);
        i = p & 63;
        scale = Q_SCALE;
    } else {
        idx -= QP;
        if (idx >= SEQ * (NKV * DH / 2)) return;
        s = idx >> 8; int p = idx & 255;
        col = KOFF + ((p >> 6) * DH) + 2 * (p & 63);
        i = p & 63;
        scale = 1.0f;
    }
    float2 cs = tab[(s << 6) + i];
    float c = cs.x, sn = cs.y;
    uint32_t u = *(const uint32_t*)(qkv + (size_t)s * NC + col);
    float x1 = __uint_as_float((u & 0xffffu) << 16);
    float x2 = __uint_as_float(u & 0xffff0000u);
    float o1 = (x1 * c - x2 * sn) * scale;
    float o2 = (x1 * sn + x2 * c) * scale;
    bf16 h1 = f2bf(o1), h2 = f2bf(o2);
    uint32_t out = ((uint32_t)(*(unsigned short*)&h2) << 16) | (uint32_t)(*(unsigned short*)&h1);
    *(uint32_t*)(qkv + (size_t)s * NC + col) = out;
}

// ---------------- V transpose via LDS tile: vt[kv][d][s] ----------------
// 64x64 tiles; both global sides coalesced (old version read at 6 KB/lane stride).
__global__ void vtrans(const bf16* __restrict__ qkv, bf16* __restrict__ vt) {
    __shared__ bf16 tl[64][72];
    const int t = threadIdx.x;
    const int s0 = (int)(blockIdx.x >> 3) * 64;   // seq tile
    const int c0 = (int)(blockIdx.x & 7) * 64;    // v-col tile (kv*128+d space)
    {
        int r = t >> 2, cc = (t & 3) * 16;
        const bf16* p = qkv + (size_t)(s0 + r) * NC + VOFF + c0 + cc;
        *(bf16x8*)&tl[r][cc]     = *(const bf16x8*)p;
        *(bf16x8*)&tl[r][cc + 8] = *(const bf16x8*)(p + 8);
    }
    __syncthreads();
    {
        int dd = t >> 2, sc = (t & 3) * 16;
        int col = c0 + dd;                        // = kv*128 + d
        bf16 tmp[16];
        #pragma unroll
        for (int j = 0; j < 16; ++j) tmp[j] = tl[sc + j][dd];
        bf16* q = vt + (size_t)col * SEQ + s0 + sc;
        *(bf16x8*)q       = *(bf16x8*)&tmp[0];
        *(bf16x8*)(q + 8) = *(bf16x8*)&tmp[8];
    }
}

// ---------------- flash attention v6 ----------------
// 512 blocks x 256 thr. Block = (q-tile pair, KV group, head-pair); 65 iters each
// (balanced). 4 waves = 2 row-chunks(16) x 2 key-halves(32). 3 blocks/CU target
// (12 waves/CU) -- independent barrier groups hide each other's serial chains.
// Swapped QK^T + in-register P via cvt_pk/permlane32_swap (T12); linear l merge.
#define LQK 136   // Ks row stride (elems)
#define LV  72    // Vs row stride

__global__ __launch_bounds__(256, 3)
void flash(const bf16* __restrict__ qkv, const bf16* __restrict__ vt,
           bf16* __restrict__ z) {
    __shared__ char smem[36352];
    bf16*  Ks  = (bf16*)smem;                    // 64 x LQK = 17408 B
    bf16*  Vs  = (bf16*)(smem + 17408);          // 128 x LV = 18432 B
    float* lml = (float*)(smem + 35840);         // 4 x 32   =   512 B
    float* ob  = (float*)smem;                   // merge reuse: 2*32*128 f32 = 32768 B

    const int tid = threadIdx.x;
    const int wave = tid >> 6, lane = tid & 63;
    const int l31 = lane & 31, lh = lane >> 5;
    const int ch = wave >> 1;         // row chunk (16 rows)
    const int kh = wave & 1;          // key half (32 keys)
    const int bx = blockIdx.x;
    const int pairidx = bx >> 3;      // 0..63
    const int g = (bx >> 1) & 3;      // KV group
    const int hp = bx & 1;            // head pair within group

    const int kr = tid >> 2, kc = (tid & 3) * 32;   // K staging: 4 chunks/thread
    const int vd = tid >> 1, vc = (tid & 1) * 32;   // V staging: 4 chunks/thread

    #pragma unroll 1
    for (int tt = 0; tt < 2; ++tt) {
        const int qt = tt ? (127 - pairidx) : pairidx;
        const int r_base = qt * 32 + ch * 16;
        const int ktmax = qt >> 1;

        // Q -> registers (B operand): lane n=l31 -> q-row; k = lh*8 + s*16 + j
        bf16x8 qf[8];
        {
            const int qrow = r_base + (l31 & 15);
            const int head = g * 4 + hp * 2 + (l31 >> 4);
            const bf16* qp = qkv + (size_t)qrow * NC + head * DH + lh * 8;
            #pragma unroll
            for (int s = 0; s < 8; ++s)
                qf[s] = *(const bf16x8*)(qp + s * 16);
        }

        // prologue: prefetch K/V tile 0 into registers
        const bf16* kp = qkv + (size_t)kr * NC + KOFF + g * DH + kc;
        const bf16* vp = vt + ((size_t)g * DH + vd) * SEQ + vc;
        bf16x8 krg[4], vrg[4];
        #pragma unroll
        for (int q = 0; q < 4; ++q) { krg[q] = *(const bf16x8*)(kp + q * 8); }
        #pragma unroll
        for (int q = 0; q < 4; ++q) { vrg[q] = *(const bf16x8*)(vp + q * 8); }

        f32x16 o_acc[4] = {};
        float lsum = 0.0f;

        for (int kt = 0; kt <= ktmax; ++kt) {
            __syncthreads();   // all waves done reading Ks/Vs of prev iter
            #pragma unroll
            for (int q = 0; q < 4; ++q)
                *(bf16x8*)&Ks[kr * LQK + kc + q * 8] = krg[q];
            #pragma unroll
            for (int q = 0; q < 4; ++q)
                *(bf16x8*)&Vs[vd * LV + vc + q * 8] = vrg[q];
            __syncthreads();

            if (kt < ktmax) {  // prefetch next tile; drains during compute
                kp += (size_t)64 * NC; vp += 64;
                #pragma unroll
                for (int q = 0; q < 4; ++q) { krg[q] = *(const bf16x8*)(kp + q * 8); }
                #pragma unroll
                for (int q = 0; q < 4; ++q) { vrg[q] = *(const bf16x8*)(vp + q * 8); }
            }

            const int key_min = kt * 64 + kh * 32;
            if (key_min <= r_base + 15) {   // some key unmasked for this chunk
                // S^T = K Q^T : lane l31 = q-row, regs = 16 keys
                f32x16 sacc = {};
                __builtin_amdgcn_s_setprio(1);
                #pragma unroll
                for (int s = 0; s < 8; ++s) {
                    bf16x8 kb = *(const bf16x8*)&Ks[(kh * 32 + l31) * LQK + lh * 8 + s * 16];
                    sacc = __builtin_amdgcn_mfma_f32_32x32x16_bf16(kb, qf[s], sacc, 0, 0, 0);
                }
                __builtin_amdgcn_s_setprio(0);

                const bool needmask = (key_min + 31 > r_base);
                const int qrow = r_base + (l31 & 15);
                float e[16];
                if (needmask) {   // diagonal tile only (~1 of 33 iters)
                    #pragma unroll
                    for (int rg = 0; rg < 16; ++rg) {
                        const int keyg = key_min + (rg & 3) + 8 * (rg >> 2) + 4 * lh;
                        float sv = sacc[rg];
                        if (keyg > qrow) sv = -INFINITY;
                        e[rg] = exp2f(sv);
                    }
                } else {
                    #pragma unroll
                    for (int rg = 0; rg < 16; ++rg)
                        e[rg] = exp2f(sacc[rg]);
                }
                // tree-sum into lsum (short dep chain)
                {
                    float t0 = (e[0] + e[1]) + (e[2] + e[3]);
                    float t1 = (e[4] + e[5]) + (e[6] + e[7]);
                    float t2 = (e[8] + e[9]) + (e[10] + e[11]);
                    float t3 = (e[12] + e[13]) + (e[14] + e[15]);
                    lsum += (t0 + t1) + (t2 + t3);
                }

                // P -> A fragments in-register (T12)
                bf16x8 pa[2];
                #pragma unroll
                for (int s2 = 0; s2 < 2; ++s2) {
                    uint32_t wA0, wA1, wB0, wB1;
                    asm("v_cvt_pk_bf16_f32 %0, %1, %2" : "=v"(wA0) : "v"(e[8*s2+0]), "v"(e[8*s2+1]));
                    asm("v_cvt_pk_bf16_f32 %0, %1, %2" : "=v"(wA1) : "v"(e[8*s2+2]), "v"(e[8*s2+3]));
                    asm("v_cvt_pk_bf16_f32 %0, %1, %2" : "=v"(wB0) : "v"(e[8*s2+4]), "v"(e[8*s2+5]));
                    asm("v_cvt_pk_bf16_f32 %0, %1, %2" : "=v"(wB1) : "v"(e[8*s2+6]), "v"(e[8*s2+7]));
                    asm volatile("v_permlane32_swap_b32 %0, %1" : "+v"(wA0), "+v"(wB0));
                    asm volatile("v_permlane32_swap_b32 %0, %1" : "+v"(wA1), "+v"(wB1));
                    union { uint32_t u[4]; bf16x8 v; } cvt;
                    cvt.u[0] = wA0; cvt.u[1] = wA1; cvt.u[2] = wB0; cvt.u[3] = wB1;
                    pa[s2] = cvt.v;
                }

                // PV: A = P fragments (in-reg), B = V^T fragments from LDS
                __builtin_amdgcn_s_setprio(1);
                #pragma unroll
                for (int nt = 0; nt < 4; ++nt) {
                    #pragma unroll
                    for (int s2 = 0; s2 < 2; ++s2) {
                        bf16x8 vb = *(const bf16x8*)&Vs[(nt * 32 + l31) * LV + kh * 32 + lh * 8 + s2 * 16];
                        o_acc[nt] = __builtin_amdgcn_mfma_f32_32x32x16_bf16(pa[s2], vb, o_acc[nt], 0, 0, 0);
                    }
                }
                __builtin_amdgcn_s_setprio(0);
            }
        }

        // merge lh halves of l in-register
        float la = lsum, lb = lsum;
        asm volatile("v_permlane32_swap_b32 %0, %1" : "+v"(la), "+v"(lb));
        const float l_tot = la + lb;   // full 32-key-half sum for q-row l31

        // ---- merge key-half partials (linear: no max alignment needed) ----
        __syncthreads();               // all compute done; Ks/Vs region free for ob
        if (lh == 0) lml[wave * 32 + l31] = l_tot;
        if (kh == 1) {
            #pragma unroll
            for (int nt = 0; nt < 4; ++nt)
                #pragma unroll
                for (int rg = 0; rg < 16; ++rg) {
                    const int m = (rg & 3) + 8 * (rg >> 2) + 4 * lh;
                    ob[(ch * 32 + m) * 128 + nt * 32 + l31] = o_acc[nt][rg];
                }
        }
        __syncthreads();
        if (kh == 0) {
            float invl[16];
            #pragma unroll
            for (int rg = 0; rg < 16; ++rg) {
                const int m = (rg & 3) + 8 * (rg >> 2) + 4 * lh;
                invl[rg] = 1.0f / (lml[wave * 32 + m] + lml[(wave + 1) * 32 + m]);
            }
            #pragma unroll
            for (int nt = 0; nt < 4; ++nt)
                #pragma unroll
                for (int rg = 0; rg < 16; ++rg) {
                    const int m = (rg & 3) + 8 * (rg >> 2) + 4 * lh;
                    float oo = o_acc[nt][rg] + ob[(ch * 32 + m) * 128 + nt * 32 + l31];
                    const int row = r_base + (m & 15);
                    const int col = (g * 4 + hp * 2 + (m >> 4)) * DH + nt * 32 + l31;
                    z[(size_t)row * DM + col] = f2bf(oo * invl[rg]);
                }
        }
        __syncthreads();               // ob/lml reads done before next tt staging
    }
}

// ---------------- launch ----------------
extern "C" void kernel_launch(void* const* d_in, const int* in_sizes, int n_in,
                              void* d_out, int out_size, void* d_ws, size_t ws_size,
                              hipStream_t stream) {
    const float* x  = (const float*)d_in[0];
    const float* WQ = (const float*)d_in[1];
    const float* WK = (const float*)d_in[2];
    const float* WV = (const float*)d_in[3];
    const float* WO = (const float*)d_in[4];
    const float* bQ = (const float*)d_in[5];
    const float* bK = (const float*)d_in[6];
    const float* bV = (const float*)d_in[7];
    const float* bO = (const float*)d_in[8];
    float* out = (float*)d_out;

    char* ws = (char*)d_ws;
    bf16*  wt_cat = (bf16*)(ws);                  // 12,582,912
    bf16*  wt_o   = (bf16*)(ws + 12582912);       //  8,388,608
    float* bias_c = (float*)(ws + 20971520);      //  16,384 (padded)
    bf16*  qkv    = (bf16*)(ws + 20987904);       // 25,165,824
    bf16*  vt     = (bf16*)(ws + 46153728);       //  4,194,304
    bf16*  z      = (bf16*)(ws + 50348032);       // 16,777,216
    bf16*  xb     = (bf16*)(ws + 67125248);       // 16,777,216 (dead after gemm1 -> sincos table)
    float2* sct   = (float2*)xb;                  //  2,097,152 (reuse)

    xconv    <<<8192, 256, 0, stream>>>(x, xb);
    prep_wqkv<<<dim3(8, 3072), 256, 0, stream>>>(WQ, WK, WV, wt_cat);
    prep_wo  <<<dim3(8, 2048), 256, 0, stream>>>(WO, wt_o);
    prep_bias<<<12, 256, 0, stream>>>(bQ, bK, bV, bias_c);
    gemm_bt<bf16> <<<dim3(24, 32), 256, 0, stream>>>(xb, wt_cat, bias_c, qkv, NC);
    sctab    <<<1024, 256, 0, stream>>>(sct);
    rotary   <<<20480, 256, 0, stream>>>(qkv, sct);
    vtrans   <<<512, 256, 0, stream>>>(qkv, vt);
    flash    <<<512, 256, 0, stream>>>(qkv, vt, z);
    gemm_bt<float><<<dim3(16, 32), 256, 0, stream>>>(z, wt_o, bO, out, DM);
}

// Round 4
// 388.346 us; speedup vs baseline: 1.2048x; 1.2048x over previous
//
#include <hip/hip_runtime.h>
#include <hip/hip_bf16.h>
#include <cstdint>
#include <cstddef>

#define SEQ    4096
#define DM     2048
#define DH     128
#define NH     16
#define NKV    4
#define NC     3072          // qkv output columns: 2048 q | 512 k | 512 v
#define KOFF   2048
#define VOFF   2560
// 1/sqrt(128) * log2(e): q pre-scale so softmax runs in base-2 (exp2)
#define Q_SCALE 0.12751730f

using bf16 = __hip_bfloat16;
typedef __bf16 bf16x8 __attribute__((ext_vector_type(8)));
typedef float f32x4 __attribute__((ext_vector_type(4)));
typedef float f32x16 __attribute__((ext_vector_type(16)));

static __device__ inline float bf2f(bf16 x) { return __bfloat162float(x); }
static __device__ inline bf16 f2bf(float x) { return __float2bfloat16(x); }

// async global->LDS, 16B per lane. LDS dest = wave-uniform base + lane*16.
static __device__ inline void load_lds16(const bf16* g, bf16* l) {
    __builtin_amdgcn_global_load_lds(
        (const __attribute__((address_space(1))) uint32_t*)g,
        (__attribute__((address_space(3))) uint32_t*)l, 16, 0, 0);
}

// ---------------- x: f32 -> bf16 ----------------
__global__ void xconv(const float* __restrict__ in, bf16* __restrict__ out) {
    int i = blockIdx.x * 256 + threadIdx.x;   // one float4 per thread
    float4 v = ((const float4*)in)[i];
    bf16 a = f2bf(v.x), b = f2bf(v.y), c = f2bf(v.z), d = f2bf(v.w);
    ushort4 u;
    u.x = *(unsigned short*)&a; u.y = *(unsigned short*)&b;
    u.z = *(unsigned short*)&c; u.w = *(unsigned short*)&d;
    ((ushort4*)out)[i] = u;
}

// ---------------- prep: weight transposes (f32 -> bf16) + bias concat ----------------
__global__ void prep_wqkv(const float* __restrict__ WQ, const float* __restrict__ WK,
                          const float* __restrict__ WV, bf16* __restrict__ wt) {
    int m = blockIdx.x * 256 + threadIdx.x;   // 0..2047
    int j = blockIdx.y;                       // 0..3071
    float v;
    if (j < KOFF)      { v = WQ[((size_t)(j >> 7) * DM + m) * DH + (j & 127)]; }
    else if (j < VOFF) { int jj = j - KOFF; v = WK[((size_t)(jj >> 7) * DM + m) * DH + (jj & 127)]; }
    else               { int jj = j - VOFF; v = WV[((size_t)(jj >> 7) * DM + m) * DH + (jj & 127)]; }
    wt[(size_t)j * DM + m] = f2bf(v);
}

__global__ void prep_wo(const float* __restrict__ WO, bf16* __restrict__ wt) {
    int m = blockIdx.x * 256 + threadIdx.x;
    int j = blockIdx.y;
    wt[(size_t)j * DM + m] = f2bf(WO[(size_t)m * DM + j]);
}

__global__ void prep_bias(const float* __restrict__ bQ, const float* __restrict__ bK,
                          const float* __restrict__ bV, float* __restrict__ bias) {
    int j = blockIdx.x * 256 + threadIdx.x;
    if (j >= NC) return;
    bias[j] = (j < KOFF) ? bQ[j] : (j < VOFF ? bK[j - KOFF] : bV[j - VOFF]);
}

// ---------------- GEMM: C[M][N] = A[M][2048] * Bt[N][2048]^T + bias ----------------
#define BM 128
#define BN 128
#define BK 64

template <typename OutT>
__global__ __launch_bounds__(256)
void gemm_bt(const bf16* __restrict__ A, const bf16* __restrict__ Bt,
             const float* __restrict__ bias, OutT* __restrict__ C, int N) {
    __shared__ __align__(16) bf16 As[BM * BK];   // 16 KB, linear [128][64]
    __shared__ __align__(16) bf16 Bs[BN * BK];   // 16 KB
    const int tid = threadIdx.x;
    const int wave = tid >> 6, lane = tid & 63;
    const int quad = lane >> 4, l15 = lane & 15;
    const int wm = (wave >> 1) * 64, wn = (wave & 1) * 64;
    const int m0 = blockIdx.y * BM, n0 = blockIdx.x * BN;

    f32x4 acc[4][4] = {};

    const bf16* gsrc = (wave < 2)
        ? A  + (size_t)(m0 + (wave & 1) * 64) * DM
        : Bt + (size_t)(n0 + (wave & 1) * 64) * DM;
    bf16* lbase = (wave < 2 ? As : Bs) + (wave & 1) * 64 * BK;
    const int lrow = lane >> 3;                          // 0..7
    const int gslot = (lane & 7) ^ lrow;                 // swizzled source slot
    const bf16* gp = gsrc + (size_t)lrow * DM + gslot * 8;

    const int rsw = l15 & 7;

    for (int k0 = 0; k0 < DM; k0 += BK) {
        __syncthreads();
        #pragma unroll
        for (int cc = 0; cc < 8; ++cc)
            load_lds16(gp + (size_t)cc * 8 * DM + k0, lbase + cc * 8 * BK);
        __syncthreads();

        #pragma unroll
        for (int ks = 0; ks < 2; ++ks) {
            bf16x8 af[4], bfr[4];
            #pragma unroll
            for (int i = 0; i < 4; ++i)
                af[i] = *(const bf16x8*)&As[(wm + i * 16 + l15) * BK + (((ks * 4 + quad) ^ rsw) * 8)];
            #pragma unroll
            for (int j = 0; j < 4; ++j)
                bfr[j] = *(const bf16x8*)&Bs[(wn + j * 16 + l15) * BK + (((ks * 4 + quad) ^ rsw) * 8)];
            #pragma unroll
            for (int i = 0; i < 4; ++i)
                #pragma unroll
                for (int j = 0; j < 4; ++j)
                    acc[i][j] = __builtin_amdgcn_mfma_f32_16x16x32_bf16(af[i], bfr[j], acc[i][j], 0, 0, 0);
        }
    }

    #pragma unroll
    for (int i = 0; i < 4; ++i) {
        int row = m0 + wm + i * 16 + quad * 4;
        #pragma unroll
        for (int j = 0; j < 4; ++j) {
            int col = n0 + wn + j * 16 + l15;
            float bv = bias[col];
            #pragma unroll
            for (int r = 0; r < 4; ++r) {
                float val = acc[i][j][r] + bv;
                if constexpr (sizeof(OutT) == 2)
                    C[(size_t)(row + r) * N + col] = f2bf(val);
                else
                    C[(size_t)(row + r) * N + col] = val;
            }
        }
    }
}

// ---------------- rotary: precomputed cos/sin table ----------------
__global__ void sctab(float2* __restrict__ tab) {
    int idx = blockIdx.x * 256 + threadIdx.x;   // 0..262143
    int s = idx >> 6, i = idx & 63;
    float inv_freq = __expf(-(float)i * 0.14391156831212788f);
    float ang = (float)s * inv_freq;
    float2 cs;
    cs.x = cosf(ang);
    cs.y = sinf(ang);
    tab[idx] = cs;
}

__global__ void rotary(bf16* __restrict__ qkv, const float2* __restrict__ tab) {
    int idx = blockIdx.x * 256 + threadIdx.x;
    const int QP = SEQ * (NH * DH / 2);
    int s, col, i; float scale;
    if (idx < QP) {
        s = idx >> 10; int p = idx & 1023;
        col = ((p >> 6) * DH) + 2 * (p & 63);
        i = p & 63;
        scale = Q_SCALE;
    } else {
        idx -= QP;
        if (idx >= SEQ * (NKV * DH / 2)) return;
        s = idx >> 8; int p = idx & 255;
        col = KOFF + ((p >> 6) * DH) + 2 * (p & 63);
        i = p & 63;
        scale = 1.0f;
    }
    float2 cs = tab[(s << 6) + i];
    float c = cs.x, sn = cs.y;
    uint32_t u = *(const uint32_t*)(qkv + (size_t)s * NC + col);
    float x1 = __uint_as_float((u & 0xffffu) << 16);
    float x2 = __uint_as_float(u & 0xffff0000u);
    float o1 = (x1 * c - x2 * sn) * scale;
    float o2 = (x1 * sn + x2 * c) * scale;
    bf16 h1 = f2bf(o1), h2 = f2bf(o2);
    uint32_t out = ((uint32_t)(*(unsigned short*)&h2) << 16) | (uint32_t)(*(unsigned short*)&h1);
    *(uint32_t*)(qkv + (size_t)s * NC + col) = out;
}

// ---------------- V transpose via LDS tile: vt[kv][d][s] ----------------
__global__ void vtrans(const bf16* __restrict__ qkv, bf16* __restrict__ vt) {
    __shared__ bf16 tl[64][72];
    const int t = threadIdx.x;
    const int s0 = (int)(blockIdx.x >> 3) * 64;   // seq tile
    const int c0 = (int)(blockIdx.x & 7) * 64;    // v-col tile (kv*128+d space)
    {
        int r = t >> 2, cc = (t & 3) * 16;
        const bf16* p = qkv + (size_t)(s0 + r) * NC + VOFF + c0 + cc;
        *(bf16x8*)&tl[r][cc]     = *(const bf16x8*)p;
        *(bf16x8*)&tl[r][cc + 8] = *(const bf16x8*)(p + 8);
    }
    __syncthreads();
    {
        int dd = t >> 2, sc = (t & 3) * 16;
        int col = c0 + dd;                        // = kv*128 + d
        bf16 tmp[16];
        #pragma unroll
        for (int j = 0; j < 16; ++j) tmp[j] = tl[sc + j][dd];
        bf16* q = vt + (size_t)col * SEQ + s0 + sc;
        *(bf16x8*)q       = *(bf16x8*)&tmp[0];
        *(bf16x8*)(q + 8) = *(bf16x8*)&tmp[8];
    }
}

// ---------------- flash attention v7 ----------------
// 1024 blocks x 256 thr; block = (qt, g, hp), biggest-qt-first (LPT backfill:
// longest block 64 iters << 130 iters/CU average). 4 waves = 2 ch x 2 kh.
// K/V staged via global_load_lds (zero staging VGPRs, m97 pattern); linear LDS
// rows with XOR-swizzled SOURCE block index + matching XOR on ds_read (rule 21).
// Bank math: row stride 256B/128B === 0 mod 32 banks; blk^=(row&7) spreads the
// 8 16B-blocks a 32-row read column touches across all bank quads -> uniform
// 8 dwords/bank (the 64-lane b128 minimum). Swapped QK^T + in-register P (T12).
__global__ __launch_bounds__(256, 3)
void flash(const bf16* __restrict__ qkv, const bf16* __restrict__ vt,
           bf16* __restrict__ z) {
    __shared__ char smem[33280];
    bf16*  Ks  = (bf16*)smem;                    // [64][128]  = 16384 B (swizzled)
    bf16*  Vs  = (bf16*)(smem + 16384);          // [128][64]  = 16384 B (swizzled)
    float* lml = (float*)(smem + 32768);         // 4 x 32     =   512 B
    float* ob  = (float*)smem;                   // merge reuse: 2*32*128 f32 = 32768 B

    const int tid = threadIdx.x;
    const int wave = tid >> 6, lane = tid & 63;
    const int l31 = lane & 31, lh = lane >> 5;
    const int ch = wave >> 1;         // row chunk (16 rows)
    const int kh = wave & 1;          // key half (32 keys)
    const int bx = blockIdx.x;
    const int qt = 127 - (bx >> 3);   // biggest first
    const int g = (bx >> 1) & 3;      // KV group
    const int hp = bx & 1;            // head pair within group
    const int r_base = qt * 32 + ch * 16;
    const int ktmax = qt >> 1;
    const int rsw = l31 & 7;          // read-side XOR (row&7 for both QK and PV reads)

    // staging pointers: chunk q = wave*4+i covers LDS elems [q*512, q*512+512)
    // K: row = q*4 + (lane>>4); source col block = (lane&15) ^ (row&7)
    // V: d   = q*8 + (lane>>3); source key block = (lane&7)  ^ (d&7)
    const bf16* kp[4];
    const bf16* vp[4];
    #pragma unroll
    for (int i = 0; i < 4; ++i) {
        const int q = wave * 4 + i;
        const int krow = q * 4 + (lane >> 4);
        kp[i] = qkv + KOFF + g * DH + (size_t)krow * NC + (((lane & 15) ^ (krow & 7)) * 8);
        const int vdd = q * 8 + (lane >> 3);
        vp[i] = vt + (size_t)(g * DH + vdd) * SEQ + (((lane & 7) ^ (vdd & 7)) * 8);
    }

    // Q -> registers (B operand): lane n=l31 -> q-row; k = lh*8 + s*16 + j
    bf16x8 qf[8];
    {
        const int qrow = r_base + (l31 & 15);
        const int head = g * 4 + hp * 2 + (l31 >> 4);
        const bf16* qp = qkv + (size_t)qrow * NC + head * DH + lh * 8;
        #pragma unroll
        for (int s = 0; s < 8; ++s)
            qf[s] = *(const bf16x8*)(qp + s * 16);
    }

    f32x16 o_acc[4] = {};
    float lsum = 0.0f;

    for (int kt = 0; kt <= ktmax; ++kt) {
        __syncthreads();   // all waves done reading Ks/Vs of prev iter
        #pragma unroll
        for (int i = 0; i < 4; ++i)
            load_lds16(kp[i], Ks + (wave * 4 + i) * 512);
        #pragma unroll
        for (int i = 0; i < 4; ++i)
            load_lds16(vp[i], Vs + (wave * 4 + i) * 512);
        __syncthreads();   // compiler drains vmcnt(0) before barrier
        #pragma unroll
        for (int i = 0; i < 4; ++i) { kp[i] += (size_t)64 * NC; vp[i] += 64; }

        const int key_min = kt * 64 + kh * 32;
        if (key_min <= r_base + 15) {   // some key unmasked for this chunk
            // S^T = K Q^T : lane l31 = q-row, regs = 16 keys
            f32x16 sacc = {};
            __builtin_amdgcn_s_setprio(1);
            #pragma unroll
            for (int s = 0; s < 8; ++s) {
                bf16x8 kb = *(const bf16x8*)&Ks[(kh * 32 + l31) * 128 + (((lh + 2 * s) ^ rsw) * 8)];
                sacc = __builtin_amdgcn_mfma_f32_32x32x16_bf16(kb, qf[s], sacc, 0, 0, 0);
            }
            __builtin_amdgcn_s_setprio(0);

            const bool needmask = (key_min + 31 > r_base);
            const int qrow = r_base + (l31 & 15);
            float e[16];
            if (needmask) {   // diagonal tile only (~1 of ~33 iters)
                #pragma unroll
                for (int rg = 0; rg < 16; ++rg) {
                    const int keyg = key_min + (rg & 3) + 8 * (rg >> 2) + 4 * lh;
                    float sv = sacc[rg];
                    if (keyg > qrow) sv = -INFINITY;
                    e[rg] = exp2f(sv);
                }
            } else {
                #pragma unroll
                for (int rg = 0; rg < 16; ++rg)
                    e[rg] = exp2f(sacc[rg]);
            }
            {
                float t0 = (e[0] + e[1]) + (e[2] + e[3]);
                float t1 = (e[4] + e[5]) + (e[6] + e[7]);
                float t2 = (e[8] + e[9]) + (e[10] + e[11]);
                float t3 = (e[12] + e[13]) + (e[14] + e[15]);
                lsum += (t0 + t1) + (t2 + t3);
            }

            // P -> A fragments in-register (T12)
            bf16x8 pa[2];
            #pragma unroll
            for (int s2 = 0; s2 < 2; ++s2) {
                uint32_t wA0, wA1, wB0, wB1;
                asm("v_cvt_pk_bf16_f32 %0, %1, %2" : "=v"(wA0) : "v"(e[8*s2+0]), "v"(e[8*s2+1]));
                asm("v_cvt_pk_bf16_f32 %0, %1, %2" : "=v"(wA1) : "v"(e[8*s2+2]), "v"(e[8*s2+3]));
                asm("v_cvt_pk_bf16_f32 %0, %1, %2" : "=v"(wB0) : "v"(e[8*s2+4]), "v"(e[8*s2+5]));
                asm("v_cvt_pk_bf16_f32 %0, %1, %2" : "=v"(wB1) : "v"(e[8*s2+6]), "v"(e[8*s2+7]));
                asm volatile("v_permlane32_swap_b32 %0, %1" : "+v"(wA0), "+v"(wB0));
                asm volatile("v_permlane32_swap_b32 %0, %1" : "+v"(wA1), "+v"(wB1));
                union { uint32_t u[4]; bf16x8 v; } cvt;
                cvt.u[0] = wA0; cvt.u[1] = wA1; cvt.u[2] = wB0; cvt.u[3] = wB1;
                pa[s2] = cvt.v;
            }

            // PV: A = P fragments (in-reg), B = V^T fragments from LDS
            __builtin_amdgcn_s_setprio(1);
            #pragma unroll
            for (int nt = 0; nt < 4; ++nt) {
                #pragma unroll
                for (int s2 = 0; s2 < 2; ++s2) {
                    bf16x8 vb = *(const bf16x8*)&Vs[(nt * 32 + l31) * 64 + (((kh * 4 + lh + 2 * s2) ^ rsw) * 8)];
                    o_acc[nt] = __builtin_amdgcn_mfma_f32_32x32x16_bf16(pa[s2], vb, o_acc[nt], 0, 0, 0);
                }
            }
            __builtin_amdgcn_s_setprio(0);
        }
    }

    // merge lh halves of l in-register
    float la = lsum, lb = lsum;
    asm volatile("v_permlane32_swap_b32 %0, %1" : "+v"(la), "+v"(lb));
    const float l_tot = la + lb;   // full 32-key-half sum for q-row l31

    // ---- merge key-half partials (linear: no max alignment needed) ----
    __syncthreads();               // all compute done; Ks/Vs region free for ob
    if (lh == 0) lml[wave * 32 + l31] = l_tot;
    if (kh == 1) {
        #pragma unroll
        for (int nt = 0; nt < 4; ++nt)
            #pragma unroll
            for (int rg = 0; rg < 16; ++rg) {
                const int m = (rg & 3) + 8 * (rg >> 2) + 4 * lh;
                ob[(ch * 32 + m) * 128 + nt * 32 + l31] = o_acc[nt][rg];
            }
    }
    __syncthreads();
    if (kh == 0) {
        float invl[16];
        #pragma unroll
        for (int rg = 0; rg < 16; ++rg) {
            const int m = (rg & 3) + 8 * (rg >> 2) + 4 * lh;
            invl[rg] = 1.0f / (lml[wave * 32 + m] + lml[(wave + 1) * 32 + m]);
        }
        #pragma unroll
        for (int nt = 0; nt < 4; ++nt)
            #pragma unroll
            for (int rg = 0; rg < 16; ++rg) {
                const int m = (rg & 3) + 8 * (rg >> 2) + 4 * lh;
                float oo = o_acc[nt][rg] + ob[(ch * 32 + m) * 128 + nt * 32 + l31];
                const int row = r_base + (m & 15);
                const int col = (g * 4 + hp * 2 + (m >> 4)) * DH + nt * 32 + l31;
                z[(size_t)row * DM + col] = f2bf(oo * invl[rg]);
            }
    }
}

// ---------------- launch ----------------
extern "C" void kernel_launch(void* const* d_in, const int* in_sizes, int n_in,
                              void* d_out, int out_size, void* d_ws, size_t ws_size,
                              hipStream_t stream) {
    const float* x  = (const float*)d_in[0];
    const float* WQ = (const float*)d_in[1];
    const float* WK = (const float*)d_in[2];
    const float* WV = (const float*)d_in[3];
    const float* WO = (const float*)d_in[4];
    const float* bQ = (const float*)d_in[5];
    const float* bK = (const float*)d_in[6];
    const float* bV = (const float*)d_in[7];
    const float* bO = (const float*)d_in[8];
    float* out = (float*)d_out;

    char* ws = (char*)d_ws;
    bf16*  wt_cat = (bf16*)(ws);                  // 12,582,912
    bf16*  wt_o   = (bf16*)(ws + 12582912);       //  8,388,608
    float* bias_c = (float*)(ws + 20971520);      //  16,384 (padded)
    bf16*  qkv    = (bf16*)(ws + 20987904);       // 25,165,824
    bf16*  vt     = (bf16*)(ws + 46153728);       //  4,194,304
    bf16*  z      = (bf16*)(ws + 50348032);       // 16,777,216
    bf16*  xb     = (bf16*)(ws + 67125248);       // 16,777,216 (dead after gemm1 -> sincos table)
    float2* sct   = (float2*)xb;                  //  2,097,152 (reuse)

    xconv    <<<8192, 256, 0, stream>>>(x, xb);
    prep_wqkv<<<dim3(8, 3072), 256, 0, stream>>>(WQ, WK, WV, wt_cat);
    prep_wo  <<<dim3(8, 2048), 256, 0, stream>>>(WO, wt_o);
    prep_bias<<<12, 256, 0, stream>>>(bQ, bK, bV, bias_c);
    gemm_bt<bf16> <<<dim3(24, 32), 256, 0, stream>>>(xb, wt_cat, bias_c, qkv, NC);
    sctab    <<<1024, 256, 0, stream>>>(sct);
    rotary   <<<20480, 256, 0, stream>>>(qkv, sct);
    vtrans   <<<512, 256, 0, stream>>>(qkv, vt);
    flash    <<<1024, 256, 0, stream>>>(qkv, vt, z);
    gemm_bt<float><<<dim3(16, 32), 256, 0, stream>>>(z, wt_o, bO, out, DM);
}

// Round 5
// 354.728 us; speedup vs baseline: 1.3189x; 1.0948x over previous
//
#include <hip/hip_runtime.h>
#include <hip/hip_bf16.h>
#include <cstdint>
#include <cstddef>

#define SEQ    4096
#define DM     2048
#define DH     128
#define NH     16
#define NKV    4
#define NC     3072          // qkv output columns: 2048 q | 512 k | 512 v
#define KOFF   2048
#define VOFF   2560
// 1/sqrt(128) * log2(e): q pre-scale so softmax runs in base-2 (exp2)
#define Q_SCALE 0.12751730f

using bf16 = __hip_bfloat16;
typedef __bf16 bf16x8 __attribute__((ext_vector_type(8)));
typedef float f32x4 __attribute__((ext_vector_type(4)));
typedef float f32x16 __attribute__((ext_vector_type(16)));

static __device__ inline float bf2f(bf16 x) { return __bfloat162float(x); }
static __device__ inline bf16 f2bf(float x) { return __float2bfloat16(x); }

// async global->LDS, 16B per lane. LDS dest = wave-uniform base + lane*16.
static __device__ inline void load_lds16(const bf16* g, bf16* l) {
    __builtin_amdgcn_global_load_lds(
        (const __attribute__((address_space(1))) uint32_t*)g,
        (__attribute__((address_space(3))) uint32_t*)l, 16, 0, 0);
}

// ---------------- x: f32 -> bf16 ----------------
__global__ void xconv(const float* __restrict__ in, bf16* __restrict__ out) {
    int i = blockIdx.x * 256 + threadIdx.x;   // one float4 per thread
    float4 v = ((const float4*)in)[i];
    bf16 a = f2bf(v.x), b = f2bf(v.y), c = f2bf(v.z), d = f2bf(v.w);
    ushort4 u;
    u.x = *(unsigned short*)&a; u.y = *(unsigned short*)&b;
    u.z = *(unsigned short*)&c; u.w = *(unsigned short*)&d;
    ((ushort4*)out)[i] = u;
}

// ---------------- prep: LDS-tiled weight transposes (f32 -> bf16) ----------------
// Old versions read W at 512B/8KB per-lane stride (uncoalesced transpose, ~16x
// sector overfetch). Now: 64x64 tile, coalesced float4 reads along the source
// fast axis, [64][65] f32 LDS (stride===1 mod 32 -> 2-way bank = free), coalesced
// bf16x8 writes along m.
__global__ void prep_wqkv(const float* __restrict__ WQ, const float* __restrict__ WK,
                          const float* __restrict__ WV, bf16* __restrict__ wt) {
    __shared__ float tl[64][65];
    const int t = threadIdx.x;
    const int m0 = (int)blockIdx.x * 64;            // m-tile
    const int head = (int)blockIdx.y >> 1;          // 0..23 = Q0..15,K0..3,V0..3
    const int h0 = ((int)blockIdx.y & 1) * 64;      // h-tile
    const float* src = (head < 16) ? WQ + (size_t)head * DM * DH
                     : (head < 20) ? WK + (size_t)(head - 16) * DM * DH
                                   : WV + (size_t)(head - 20) * DM * DH;
    {
        const int r = t >> 2, c = (t & 3) * 16;
        const float* p = src + (size_t)(m0 + r) * DH + h0 + c;
        #pragma unroll
        for (int kk = 0; kk < 4; ++kk) {
            float4 v = *(const float4*)(p + kk * 4);
            tl[r][c + kk * 4 + 0] = v.x; tl[r][c + kk * 4 + 1] = v.y;
            tl[r][c + kk * 4 + 2] = v.z; tl[r][c + kk * 4 + 3] = v.w;
        }
    }
    __syncthreads();
    {
        const int hh = t >> 2, ms = (t & 3) * 16;
        const int j = head * 128 + h0 + hh;         // concat row (Q|K|V)
        bf16 tmp[16];
        #pragma unroll
        for (int i = 0; i < 16; ++i) tmp[i] = f2bf(tl[ms + i][hh]);
        bf16* q = wt + (size_t)j * DM + m0 + ms;
        *(bf16x8*)q       = *(bf16x8*)&tmp[0];
        *(bf16x8*)(q + 8) = *(bf16x8*)&tmp[8];
    }
}

__global__ void prep_wo(const float* __restrict__ WO, bf16* __restrict__ wt) {
    __shared__ float tl[64][65];
    const int t = threadIdx.x;
    const int m0 = (int)blockIdx.x * 64;   // WO row tile ((n,h) dim)
    const int j0 = (int)blockIdx.y * 64;   // WO col tile (d_model)
    {
        const int r = t >> 2, c = (t & 3) * 16;
        const float* p = WO + (size_t)(m0 + r) * DM + j0 + c;
        #pragma unroll
        for (int kk = 0; kk < 4; ++kk) {
            float4 v = *(const float4*)(p + kk * 4);
            tl[r][c + kk * 4 + 0] = v.x; tl[r][c + kk * 4 + 1] = v.y;
            tl[r][c + kk * 4 + 2] = v.z; tl[r][c + kk * 4 + 3] = v.w;
        }
    }
    __syncthreads();
    {
        const int hh = t >> 2, ms = (t & 3) * 16;
        bf16 tmp[16];
        #pragma unroll
        for (int i = 0; i < 16; ++i) tmp[i] = f2bf(tl[ms + i][hh]);
        bf16* q = wt + (size_t)(j0 + hh) * DM + m0 + ms;
        *(bf16x8*)q       = *(bf16x8*)&tmp[0];
        *(bf16x8*)(q + 8) = *(bf16x8*)&tmp[8];
    }
}

__global__ void prep_bias(const float* __restrict__ bQ, const float* __restrict__ bK,
                          const float* __restrict__ bV, float* __restrict__ bias) {
    int j = blockIdx.x * 256 + threadIdx.x;
    if (j >= NC) return;
    bias[j] = (j < KOFF) ? bQ[j] : (j < VOFF ? bK[j - KOFF] : bV[j - VOFF]);
}

// ---------------- GEMM: C[M][N] = A[M][2048] * Bt[N][2048]^T + bias ----------------
#define BM 128
#define BN 128
#define BK 64

template <typename OutT>
__global__ __launch_bounds__(256)
void gemm_bt(const bf16* __restrict__ A, const bf16* __restrict__ Bt,
             const float* __restrict__ bias, OutT* __restrict__ C, int N) {
    __shared__ __align__(16) bf16 As[BM * BK];   // 16 KB, linear [128][64]
    __shared__ __align__(16) bf16 Bs[BN * BK];   // 16 KB
    const int tid = threadIdx.x;
    const int wave = tid >> 6, lane = tid & 63;
    const int quad = lane >> 4, l15 = lane & 15;
    const int wm = (wave >> 1) * 64, wn = (wave & 1) * 64;
    const int m0 = blockIdx.y * BM, n0 = blockIdx.x * BN;

    f32x4 acc[4][4] = {};

    const bf16* gsrc = (wave < 2)
        ? A  + (size_t)(m0 + (wave & 1) * 64) * DM
        : Bt + (size_t)(n0 + (wave & 1) * 64) * DM;
    bf16* lbase = (wave < 2 ? As : Bs) + (wave & 1) * 64 * BK;
    const int lrow = lane >> 3;                          // 0..7
    const int gslot = (lane & 7) ^ lrow;                 // swizzled source slot
    const bf16* gp = gsrc + (size_t)lrow * DM + gslot * 8;

    const int rsw = l15 & 7;

    for (int k0 = 0; k0 < DM; k0 += BK) {
        __syncthreads();
        #pragma unroll
        for (int cc = 0; cc < 8; ++cc)
            load_lds16(gp + (size_t)cc * 8 * DM + k0, lbase + cc * 8 * BK);
        __syncthreads();

        #pragma unroll
        for (int ks = 0; ks < 2; ++ks) {
            bf16x8 af[4], bfr[4];
            #pragma unroll
            for (int i = 0; i < 4; ++i)
                af[i] = *(const bf16x8*)&As[(wm + i * 16 + l15) * BK + (((ks * 4 + quad) ^ rsw) * 8)];
            #pragma unroll
            for (int j = 0; j < 4; ++j)
                bfr[j] = *(const bf16x8*)&Bs[(wn + j * 16 + l15) * BK + (((ks * 4 + quad) ^ rsw) * 8)];
            #pragma unroll
            for (int i = 0; i < 4; ++i)
                #pragma unroll
                for (int j = 0; j < 4; ++j)
                    acc[i][j] = __builtin_amdgcn_mfma_f32_16x16x32_bf16(af[i], bfr[j], acc[i][j], 0, 0, 0);
        }
    }

    #pragma unroll
    for (int i = 0; i < 4; ++i) {
        int row = m0 + wm + i * 16 + quad * 4;
        #pragma unroll
        for (int j = 0; j < 4; ++j) {
            int col = n0 + wn + j * 16 + l15;
            float bv = bias[col];
            #pragma unroll
            for (int r = 0; r < 4; ++r) {
                float val = acc[i][j][r] + bv;
                if constexpr (sizeof(OutT) == 2)
                    C[(size_t)(row + r) * N + col] = f2bf(val);
                else
                    C[(size_t)(row + r) * N + col] = val;
            }
        }
    }
}

// ---------------- rotary: precomputed cos/sin table ----------------
__global__ void sctab(float2* __restrict__ tab) {
    int idx = blockIdx.x * 256 + threadIdx.x;   // 0..262143
    int s = idx >> 6, i = idx & 63;
    float inv_freq = __expf(-(float)i * 0.14391156831212788f);
    float ang = (float)s * inv_freq;
    float2 cs;
    cs.x = cosf(ang);
    cs.y = sinf(ang);
    tab[idx] = cs;
}

__global__ void rotary(bf16* __restrict__ qkv, const float2* __restrict__ tab) {
    int idx = blockIdx.x * 256 + threadIdx.x;
    const int QP = SEQ * (NH * DH / 2);
    int s, col, i; float scale;
    if (idx < QP) {
        s = idx >> 10; int p = idx & 1023;
        col = ((p >> 6) * DH) + 2 * (p & 63);
        i = p & 63;
        scale = Q_SCALE;
    } else {
        idx -= QP;
        if (idx >= SEQ * (NKV * DH / 2)) return;
        s = idx >> 8; int p = idx & 255;
        col = KOFF + ((p >> 6) * DH) + 2 * (p & 63);
        i = p & 63;
        scale = 1.0f;
    }
    float2 cs = tab[(s << 6) + i];
    float c = cs.x, sn = cs.y;
    uint32_t u = *(const uint32_t*)(qkv + (size_t)s * NC + col);
    float x1 = __uint_as_float((u & 0xffffu) << 16);
    float x2 = __uint_as_float(u & 0xffff0000u);
    float o1 = (x1 * c - x2 * sn) * scale;
    float o2 = (x1 * sn + x2 * c) * scale;
    bf16 h1 = f2bf(o1), h2 = f2bf(o2);
    uint32_t out = ((uint32_t)(*(unsigned short*)&h2) << 16) | (uint32_t)(*(unsigned short*)&h1);
    *(uint32_t*)(qkv + (size_t)s * NC + col) = out;
}

// ---------------- V transpose via LDS tile: vt[kv][d][s] ----------------
__global__ void vtrans(const bf16* __restrict__ qkv, bf16* __restrict__ vt) {
    __shared__ bf16 tl[64][72];
    const int t = threadIdx.x;
    const int s0 = (int)(blockIdx.x >> 3) * 64;   // seq tile
    const int c0 = (int)(blockIdx.x & 7) * 64;    // v-col tile (kv*128+d space)
    {
        int r = t >> 2, cc = (t & 3) * 16;
        const bf16* p = qkv + (size_t)(s0 + r) * NC + VOFF + c0 + cc;
        *(bf16x8*)&tl[r][cc]     = *(const bf16x8*)p;
        *(bf16x8*)&tl[r][cc + 8] = *(const bf16x8*)(p + 8);
    }
    __syncthreads();
    {
        int dd = t >> 2, sc = (t & 3) * 16;
        int col = c0 + dd;                        // = kv*128 + d
        bf16 tmp[16];
        #pragma unroll
        for (int j = 0; j < 16; ++j) tmp[j] = tl[sc + j][dd];
        bf16* q = vt + (size_t)col * SEQ + s0 + sc;
        *(bf16x8*)q       = *(bf16x8*)&tmp[0];
        *(bf16x8*)(q + 8) = *(bf16x8*)&tmp[8];
    }
}

// ---------------- flash attention v7 ----------------
// 1024 blocks x 256 thr; block = (qt, g, hp), biggest-qt-first (LPT backfill).
// 4 waves = 2 ch x 2 kh. K/V staged via global_load_lds (zero staging VGPRs);
// linear LDS rows with XOR-swizzled SOURCE block index + matching XOR on ds_read.
// Swapped QK^T + in-register P via cvt_pk/permlane32_swap (T12); linear l merge.
__global__ __launch_bounds__(256, 3)
void flash(const bf16* __restrict__ qkv, const bf16* __restrict__ vt,
           bf16* __restrict__ z) {
    __shared__ char smem[33280];
    bf16*  Ks  = (bf16*)smem;                    // [64][128]  = 16384 B (swizzled)
    bf16*  Vs  = (bf16*)(smem + 16384);          // [128][64]  = 16384 B (swizzled)
    float* lml = (float*)(smem + 32768);         // 4 x 32     =   512 B
    float* ob  = (float*)smem;                   // merge reuse: 2*32*128 f32 = 32768 B

    const int tid = threadIdx.x;
    const int wave = tid >> 6, lane = tid & 63;
    const int l31 = lane & 31, lh = lane >> 5;
    const int ch = wave >> 1;         // row chunk (16 rows)
    const int kh = wave & 1;          // key half (32 keys)
    const int bx = blockIdx.x;
    const int qt = 127 - (bx >> 3);   // biggest first
    const int g = (bx >> 1) & 3;      // KV group
    const int hp = bx & 1;            // head pair within group
    const int r_base = qt * 32 + ch * 16;
    const int ktmax = qt >> 1;
    const int rsw = l31 & 7;          // read-side XOR (row&7 for both QK and PV reads)

    const bf16* kp[4];
    const bf16* vp[4];
    #pragma unroll
    for (int i = 0; i < 4; ++i) {
        const int q = wave * 4 + i;
        const int krow = q * 4 + (lane >> 4);
        kp[i] = qkv + KOFF + g * DH + (size_t)krow * NC + (((lane & 15) ^ (krow & 7)) * 8);
        const int vdd = q * 8 + (lane >> 3);
        vp[i] = vt + (size_t)(g * DH + vdd) * SEQ + (((lane & 7) ^ (vdd & 7)) * 8);
    }

    // Q -> registers (B operand): lane n=l31 -> q-row; k = lh*8 + s*16 + j
    bf16x8 qf[8];
    {
        const int qrow = r_base + (l31 & 15);
        const int head = g * 4 + hp * 2 + (l31 >> 4);
        const bf16* qp = qkv + (size_t)qrow * NC + head * DH + lh * 8;
        #pragma unroll
        for (int s = 0; s < 8; ++s)
            qf[s] = *(const bf16x8*)(qp + s * 16);
    }

    f32x16 o_acc[4] = {};
    float lsum = 0.0f;

    for (int kt = 0; kt <= ktmax; ++kt) {
        __syncthreads();   // all waves done reading Ks/Vs of prev iter
        #pragma unroll
        for (int i = 0; i < 4; ++i)
            load_lds16(kp[i], Ks + (wave * 4 + i) * 512);
        #pragma unroll
        for (int i = 0; i < 4; ++i)
            load_lds16(vp[i], Vs + (wave * 4 + i) * 512);
        __syncthreads();   // compiler drains vmcnt(0) before barrier
        #pragma unroll
        for (int i = 0; i < 4; ++i) { kp[i] += (size_t)64 * NC; vp[i] += 64; }

        const int key_min = kt * 64 + kh * 32;
        if (key_min <= r_base + 15) {   // some key unmasked for this chunk
            // S^T = K Q^T : lane l31 = q-row, regs = 16 keys
            f32x16 sacc = {};
            __builtin_amdgcn_s_setprio(1);
            #pragma unroll
            for (int s = 0; s < 8; ++s) {
                bf16x8 kb = *(const bf16x8*)&Ks[(kh * 32 + l31) * 128 + (((lh + 2 * s) ^ rsw) * 8)];
                sacc = __builtin_amdgcn_mfma_f32_32x32x16_bf16(kb, qf[s], sacc, 0, 0, 0);
            }
            __builtin_amdgcn_s_setprio(0);

            const bool needmask = (key_min + 31 > r_base);
            const int qrow = r_base + (l31 & 15);
            float e[16];
            if (needmask) {   // diagonal tile only (~1 of ~33 iters)
                #pragma unroll
                for (int rg = 0; rg < 16; ++rg) {
                    const int keyg = key_min + (rg & 3) + 8 * (rg >> 2) + 4 * lh;
                    float sv = sacc[rg];
                    if (keyg > qrow) sv = -INFINITY;
                    e[rg] = exp2f(sv);
                }
            } else {
                #pragma unroll
                for (int rg = 0; rg < 16; ++rg)
                    e[rg] = exp2f(sacc[rg]);
            }
            {
                float t0 = (e[0] + e[1]) + (e[2] + e[3]);
                float t1 = (e[4] + e[5]) + (e[6] + e[7]);
                float t2 = (e[8] + e[9]) + (e[10] + e[11]);
                float t3 = (e[12] + e[13]) + (e[14] + e[15]);
                lsum += (t0 + t1) + (t2 + t3);
            }

            // P -> A fragments in-register (T12)
            bf16x8 pa[2];
            #pragma unroll
            for (int s2 = 0; s2 < 2; ++s2) {
                uint32_t wA0, wA1, wB0, wB1;
                asm("v_cvt_pk_bf16_f32 %0, %1, %2" : "=v"(wA0) : "v"(e[8*s2+0]), "v"(e[8*s2+1]));
                asm("v_cvt_pk_bf16_f32 %0, %1, %2" : "=v"(wA1) : "v"(e[8*s2+2]), "v"(e[8*s2+3]));
                asm("v_cvt_pk_bf16_f32 %0, %1, %2" : "=v"(wB0) : "v"(e[8*s2+4]), "v"(e[8*s2+5]));
                asm("v_cvt_pk_bf16_f32 %0, %1, %2" : "=v"(wB1) : "v"(e[8*s2+6]), "v"(e[8*s2+7]));
                asm volatile("v_permlane32_swap_b32 %0, %1" : "+v"(wA0), "+v"(wB0));
                asm volatile("v_permlane32_swap_b32 %0, %1" : "+v"(wA1), "+v"(wB1));
                union { uint32_t u[4]; bf16x8 v; } cvt;
                cvt.u[0] = wA0; cvt.u[1] = wA1; cvt.u[2] = wB0; cvt.u[3] = wB1;
                pa[s2] = cvt.v;
            }

            // PV: A = P fragments (in-reg), B = V^T fragments from LDS
            __builtin_amdgcn_s_setprio(1);
            #pragma unroll
            for (int nt = 0; nt < 4; ++nt) {
                #pragma unroll
                for (int s2 = 0; s2 < 2; ++s2) {
                    bf16x8 vb = *(const bf16x8*)&Vs[(nt * 32 + l31) * 64 + (((kh * 4 + lh + 2 * s2) ^ rsw) * 8)];
                    o_acc[nt] = __builtin_amdgcn_mfma_f32_32x32x16_bf16(pa[s2], vb, o_acc[nt], 0, 0, 0);
                }
            }
            __builtin_amdgcn_s_setprio(0);
        }
    }

    // merge lh halves of l in-register
    float la = lsum, lb = lsum;
    asm volatile("v_permlane32_swap_b32 %0, %1" : "+v"(la), "+v"(lb));
    const float l_tot = la + lb;   // full 32-key-half sum for q-row l31

    // ---- merge key-half partials (linear: no max alignment needed) ----
    __syncthreads();               // all compute done; Ks/Vs region free for ob
    if (lh == 0) lml[wave * 32 + l31] = l_tot;
    if (kh == 1) {
        #pragma unroll
        for (int nt = 0; nt < 4; ++nt)
            #pragma unroll
            for (int rg = 0; rg < 16; ++rg) {
                const int m = (rg & 3) + 8 * (rg >> 2) + 4 * lh;
                ob[(ch * 32 + m) * 128 + nt * 32 + l31] = o_acc[nt][rg];
            }
    }
    __syncthreads();
    if (kh == 0) {
        float invl[16];
        #pragma unroll
        for (int rg = 0; rg < 16; ++rg) {
            const int m = (rg & 3) + 8 * (rg >> 2) + 4 * lh;
            invl[rg] = 1.0f / (lml[wave * 32 + m] + lml[(wave + 1) * 32 + m]);
        }
        #pragma unroll
        for (int nt = 0; nt < 4; ++nt)
            #pragma unroll
            for (int rg = 0; rg < 16; ++rg) {
                const int m = (rg & 3) + 8 * (rg >> 2) + 4 * lh;
                float oo = o_acc[nt][rg] + ob[(ch * 32 + m) * 128 + nt * 32 + l31];
                const int row = r_base + (m & 15);
                const int col = (g * 4 + hp * 2 + (m >> 4)) * DH + nt * 32 + l31;
                z[(size_t)row * DM + col] = f2bf(oo * invl[rg]);
            }
    }
}

// ---------------- launch ----------------
extern "C" void kernel_launch(void* const* d_in, const int* in_sizes, int n_in,
                              void* d_out, int out_size, void* d_ws, size_t ws_size,
                              hipStream_t stream) {
    const float* x  = (const float*)d_in[0];
    const float* WQ = (const float*)d_in[1];
    const float* WK = (const float*)d_in[2];
    const float* WV = (const float*)d_in[3];
    const float* WO = (const float*)d_in[4];
    const float* bQ = (const float*)d_in[5];
    const float* bK = (const float*)d_in[6];
    const float* bV = (const float*)d_in[7];
    const float* bO = (const float*)d_in[8];
    float* out = (float*)d_out;

    char* ws = (char*)d_ws;
    bf16*  wt_cat = (bf16*)(ws);                  // 12,582,912
    bf16*  wt_o   = (bf16*)(ws + 12582912);       //  8,388,608
    float* bias_c = (float*)(ws + 20971520);      //  16,384 (padded)
    bf16*  qkv    = (bf16*)(ws + 20987904);       // 25,165,824
    bf16*  vt     = (bf16*)(ws + 46153728);       //  4,194,304
    bf16*  z      = (bf16*)(ws + 50348032);       // 16,777,216
    bf16*  xb     = (bf16*)(ws + 67125248);       // 16,777,216 (dead after gemm1 -> sincos table)
    float2* sct   = (float2*)xb;                  //  2,097,152 (reuse)

    xconv    <<<8192, 256, 0, stream>>>(x, xb);
    prep_wqkv<<<dim3(32, 48), 256, 0, stream>>>(WQ, WK, WV, wt_cat);
    prep_wo  <<<dim3(32, 32), 256, 0, stream>>>(WO, wt_o);
    prep_bias<<<12, 256, 0, stream>>>(bQ, bK, bV, bias_c);
    gemm_bt<bf16> <<<dim3(24, 32), 256, 0, stream>>>(xb, wt_cat, bias_c, qkv, NC);
    sctab    <<<1024, 256, 0, stream>>>(sct);
    rotary   <<<20480, 256, 0, stream>>>(qkv, sct);
    vtrans   <<<512, 256, 0, stream>>>(qkv, vt);
    flash    <<<1024, 256, 0, stream>>>(qkv, vt, z);
    gemm_bt<float><<<dim3(16, 32), 256, 0, stream>>>(z, wt_o, bO, out, DM);
}